// Round 2
// 481.604 us; speedup vs baseline: 1.1411x; 1.1411x over previous
//
#include <hip/hip_runtime.h>

#define N 2048
#define NG 8

__device__ __forceinline__ float lrelu(float x) { return x > 0.f ? x : 0.2f * x; }

// ---------- fused: h1 (blocks 0..511) + agg/edge/colstats (blocks 512..4607) ----------
__global__ __launch_bounds__(256) void aggh1K(const float* __restrict__ attn,
                                              const float* __restrict__ w_agg,
                                              const float* __restrict__ b_agg,
                                              const float* __restrict__ x,
                                              const float* __restrict__ W1,
                                              const float* __restrict__ att_src1,
                                              const float* __restrict__ att_dst1,
                                              const float* __restrict__ We1, const float* __restrict__ att_e1,
                                              const float* __restrict__ We2, const float* __restrict__ att_e2,
                                              float* __restrict__ edge_out,
                                              float* __restrict__ colSum, float* __restrict__ colCnt,
                                              float* __restrict__ h1, float* __restrict__ a_s1, float* __restrict__ a_d1,
                                              float* __restrict__ we) {
  __shared__ float smem[512];  // h1: xr[4][128]; agg: [0..11]=wsh, [32..63]=cs, [64..95]=cc
  int tid = threadIdx.x;
  if (blockIdx.x < 512) {
    // ---- h1 = x @ W1, a_s1, a_d1; block 0 also computes we[] ----
    float* xr = smem;
    int n0 = blockIdx.x * 4;
    if (blockIdx.x == 0) {
      float v1 = We1[tid] * att_e1[tid];
#pragma unroll
      for (int off = 32; off > 0; off >>= 1) v1 += __shfl_down(v1, off);
      int lane = tid & 63, wid = tid >> 6;
      if (lane == 0) we[wid] = v1;
      float v2 = (tid < 64) ? We2[tid] * att_e2[tid] : 0.f;
#pragma unroll
      for (int off = 32; off > 0; off >>= 1) v2 += __shfl_down(v2, off);
      if (tid == 0) we[4] = v2;
    }
    for (int t = tid; t < 512; t += 256) xr[t] = x[n0 * 128 + t];
    __syncthreads();
    float acc[4] = {0.f, 0.f, 0.f, 0.f};
    for (int k = 0; k < 128; ++k) {
      float wv = W1[k * 256 + tid];
#pragma unroll
      for (int r = 0; r < 4; ++r) acc[r] += xr[r * 128 + k] * wv;
    }
    float asw = att_src1[tid], adw = att_dst1[tid];
    int lane = tid & 63, head = tid >> 6;
#pragma unroll
    for (int r = 0; r < 4; ++r) {
      h1[(size_t)(n0 + r) * 256 + tid] = acc[r];
      float ps = acc[r] * asw, pd = acc[r] * adw;
#pragma unroll
      for (int off = 32; off > 0; off >>= 1) { ps += __shfl_down(ps, off); pd += __shfl_down(pd, off); }
      if (lane == 0) { a_s1[(n0 + r) * 4 + head] = ps; a_d1[(n0 + r) * 4 + head] = pd; }
    }
  } else {
    // ---- agg: 1x1 conv over 12 maps, relu -> edge_out, column stats (no transpose needed) ----
    float* wsh = smem;
    float* cs = smem + 32;
    float* cc = smem + 64;
    int bidA = blockIdx.x - 512;
    int tx = tid & 31, ty = tid >> 5;
    if (tid < 12) wsh[tid] = w_agg[tid];
    if (tid < 32) { cs[tid] = 0.f; cc[tid] = 0.f; }
    __syncthreads();
    int i0 = (bidA >> 6) * 32, j0 = (bidA & 63) * 32;
    int j = j0 + tx;
    float bb = b_agg[0];
#pragma unroll
    for (int r = 0; r < 4; ++r) {
      int i = i0 + ty + 8 * r;
      const float* p = attn + (size_t)i * N + j;
      float v = bb;
#pragma unroll
      for (int k = 0; k < 12; ++k) v += wsh[k] * p[(size_t)k * N * N];
      float e = v > 0.f ? v : 0.f;
      edge_out[(size_t)i * N + j] = e;
      if (e > 0.f && i != j) { atomicAdd(&cs[tx], e); atomicAdd(&cc[tx], 1.f); }
    }
    __syncthreads();
    if (tid < 32) {
      atomicAdd(&colSum[j0 + tid], cs[tid]);
      atomicAdd(&colCnt[j0 + tid], cc[tid]);
    }
  }
}

// ---------- layer1 PV (unnormalized softmax, z via atomics) ----------
// grid (32,16): 64-d tile x 128-s chunk; reads edge_out[s][d] directly (float4, contiguous in d)
__global__ __launch_bounds__(256) void pv1K(const float* __restrict__ edge, const float* __restrict__ h1,
                                            const float* __restrict__ a_s1, const float* __restrict__ a_d1,
                                            const float* __restrict__ colSum, const float* __restrict__ colCnt,
                                            const float* __restrict__ we,
                                            float* __restrict__ partials, float* __restrict__ z1) {
  __shared__ float hT[16][260];   // [ss][c]   c = 0..255
  __shared__ float pL[16][260];   // [ss][h*64+dd]
  int tid = threadIdx.x;
  int d0 = blockIdx.x * 64;
  int sBeg = blockIdx.y * 128;
  float w0 = we[0], w1 = we[1], w2 = we[2], w3 = we[3];
  // p-compute indexing
  int ssp = tid & 15, dq = tid >> 4;   // dd = dq*4+q
  float4 ad4[4];
  float me_[4];
#pragma unroll
  for (int q = 0; q < 4; ++q) {
    int d = d0 + dq * 4 + q;
    ad4[q] = *(const float4*)(a_d1 + d * 4);
    float c = colCnt[d];
    me_[q] = c > 0.f ? colSum[d] / c : 0.f;
  }
  float zac[4][4];
#pragma unroll
  for (int q = 0; q < 4; ++q)
#pragma unroll
    for (int h = 0; h < 4; ++h) zac[q][h] = 0.f;
  // FMA indexing
  int dg = tid & 7;
  int cb = (tid >> 3) * 8;     // global channel base (includes head)
  int hh = tid >> 6;           // head (wave-uniform)
  float acc[8][8];
#pragma unroll
  for (int i = 0; i < 8; ++i)
#pragma unroll
    for (int j = 0; j < 8; ++j) acc[i][j] = 0.f;

  int c4 = (tid & 63) * 4;
  int rb = (tid >> 6) * 4;

#pragma unroll 1
  for (int s0 = sBeg; s0 < sBeg + 128; s0 += 16) {
    // stage hT (per-wave contiguous rows -> conflict-free b128 writes)
#pragma unroll
    for (int p4 = 0; p4 < 4; ++p4) {
      int r = rb + p4;
      *(float4*)(&hT[r][c4]) = *(const float4*)(h1 + (size_t)(s0 + r) * 256 + c4);
    }
    // p-compute (edge row-major: thread's 4 d-values are one contiguous float4)
    {
      int s = s0 + ssp;
      float4 as4 = *(const float4*)(a_s1 + s * 4);
      float4 av4 = *(const float4*)(edge + (size_t)s * N + d0 + dq * 4);
      float ev_[4] = {av4.x, av4.y, av4.z, av4.w};
      float pq[4][4];
#pragma unroll
      for (int q = 0; q < 4; ++q) {
        int d = d0 + dq * 4 + q;
        float av = ev_[q];
        float ev; bool inc;
        if (s == d) { ev = me_[q]; inc = true; } else { ev = av; inc = av > 0.f; }
        float p0 = inc ? __expf(lrelu(as4.x + ad4[q].x + ev * w0)) : 0.f;
        float p1 = inc ? __expf(lrelu(as4.y + ad4[q].y + ev * w1)) : 0.f;
        float p2 = inc ? __expf(lrelu(as4.z + ad4[q].z + ev * w2)) : 0.f;
        float p3 = inc ? __expf(lrelu(as4.w + ad4[q].w + ev * w3)) : 0.f;
        pq[0][q] = p0; pq[1][q] = p1; pq[2][q] = p2; pq[3][q] = p3;
        zac[q][0] += p0; zac[q][1] += p1; zac[q][2] += p2; zac[q][3] += p3;
      }
#pragma unroll
      for (int h = 0; h < 4; ++h)
        *(float4*)(&pL[ssp][h * 64 + dq * 4]) = make_float4(pq[h][0], pq[h][1], pq[h][2], pq[h][3]);
    }
    __syncthreads();
#pragma unroll
    for (int ss = 0; ss < 16; ++ss) {
      float4 pA = *(const float4*)(&pL[ss][hh * 64 + dg * 8]);
      float4 pB = *(const float4*)(&pL[ss][hh * 64 + dg * 8 + 4]);
      float4 hA = *(const float4*)(&hT[ss][cb]);
      float4 hB = *(const float4*)(&hT[ss][cb + 4]);
      float pv[8] = {pA.x, pA.y, pA.z, pA.w, pB.x, pB.y, pB.z, pB.w};
      float hv[8] = {hA.x, hA.y, hA.z, hA.w, hB.x, hB.y, hB.z, hB.w};
#pragma unroll
      for (int di = 0; di < 8; ++di)
#pragma unroll
        for (int ci = 0; ci < 8; ++ci) acc[di][ci] += pv[di] * hv[ci];
    }
    __syncthreads();
  }
  float* outp = partials + (size_t)blockIdx.y * ((size_t)N * 256);
#pragma unroll
  for (int di = 0; di < 8; ++di) {
    size_t rowo = (size_t)(d0 + dg * 8 + di) * 256 + cb;
    *(float4*)(outp + rowo) = make_float4(acc[di][0], acc[di][1], acc[di][2], acc[di][3]);
    *(float4*)(outp + rowo + 4) = make_float4(acc[di][4], acc[di][5], acc[di][6], acc[di][7]);
  }
  // z reduction over ssp (16-lane groups), then atomics
#pragma unroll
  for (int q = 0; q < 4; ++q)
#pragma unroll
    for (int h = 0; h < 4; ++h) {
      float v = zac[q][h];
      v += __shfl_down(v, 8); v += __shfl_down(v, 4);
      v += __shfl_down(v, 2); v += __shfl_down(v, 1);
      if (ssp == 0) atomicAdd(&z1[(d0 + dq * 4 + q) * 4 + h], v);
    }
}

// ---------- layer2 features fused with layer1 finalize ----------
__global__ __launch_bounds__(256) void h2K(const float* __restrict__ partials, const float* __restrict__ z1,
                                           const float* __restrict__ bias1,
                                           const float* __restrict__ W2,
                                           const float* __restrict__ att_src2, const float* __restrict__ att_dst2,
                                           float* __restrict__ hh2, float* __restrict__ a_s2, float* __restrict__ a_d2) {
  __shared__ float hr[4][256];
  int tid = threadIdx.x;
  int n0 = blockIdx.x * 4;
  for (int e = tid; e < 1024; e += 256) {
    int node = e >> 8, c = e & 255;
    size_t base = (size_t)(n0 + node) * 256 + c;
    float sAcc = 0.f;
#pragma unroll
    for (int q = 0; q < 16; ++q) sAcc += partials[(size_t)q * N * 256 + base];
    float a = sAcc / z1[(n0 + node) * 4 + (c >> 6)] + bias1[c];
    hr[node][c] = a > 0.f ? a : __expf(a) - 1.f;
  }
  __syncthreads();
  int c = tid & 63, nl = tid >> 6;
  float acc = 0.f;
  for (int k = 0; k < 256; ++k) acc += hr[nl][k] * W2[k * 64 + c];
  hh2[(size_t)(n0 + nl) * 64 + c] = acc;
  float ps = acc * att_src2[c], pd = acc * att_dst2[c];
#pragma unroll
  for (int off = 32; off > 0; off >>= 1) { ps += __shfl_down(ps, off); pd += __shfl_down(pd, off); }
  if (c == 0) { a_s2[n0 + nl] = ps; a_d2[n0 + nl] = pd; }
}

// ---------- layer2 PV (unnormalized, z via atomics), grid (16,32) ----------
__global__ __launch_bounds__(256) void pv2K(const float* __restrict__ edge, const float* __restrict__ hh2,
                                            const float* __restrict__ a_s2, const float* __restrict__ a_d2,
                                            const float* __restrict__ colSum, const float* __restrict__ colCnt,
                                            const float* __restrict__ we,
                                            float* __restrict__ partials, float* __restrict__ z2) {
  __shared__ float hT[16][68];    // [ss][c]  c = 0..63
  __shared__ float pL[16][132];   // [ss][dd] dd = 0..127
  int tid = threadIdx.x;
  int d0 = blockIdx.x * 128;
  int sBeg = blockIdx.y * 64;
  float wE = we[4];
  int ssp = tid & 15, dq = tid >> 4;   // dd = dq*8+q
  float adv[8], me_[8];
#pragma unroll
  for (int q = 0; q < 8; ++q) {
    int d = d0 + dq * 8 + q;
    adv[q] = a_d2[d];
    float c = colCnt[d];
    me_[q] = c > 0.f ? colSum[d] / c : 0.f;
  }
  float zac[8];
#pragma unroll
  for (int q = 0; q < 8; ++q) zac[q] = 0.f;
  int dg = tid & 15;   // d = d0 + dg*8 + di
  int cg = tid >> 4;   // c = cg*4 + ci
  float acc[8][4];
#pragma unroll
  for (int i = 0; i < 8; ++i)
#pragma unroll
    for (int j = 0; j < 4; ++j) acc[i][j] = 0.f;

  int stR = tid >> 4, stC = (tid & 15) * 4;

#pragma unroll 1
  for (int s0 = sBeg; s0 < sBeg + 64; s0 += 16) {
    *(float4*)(&hT[stR][stC]) = *(const float4*)(hh2 + (size_t)(s0 + stR) * 64 + stC);
    {
      int s = s0 + ssp;
      float asv = a_s2[s];
      float4 eA = *(const float4*)(edge + (size_t)s * N + d0 + dq * 8);
      float4 eB = *(const float4*)(edge + (size_t)s * N + d0 + dq * 8 + 4);
      float ev_[8] = {eA.x, eA.y, eA.z, eA.w, eB.x, eB.y, eB.z, eB.w};
      float pq[8];
#pragma unroll
      for (int q = 0; q < 8; ++q) {
        int d = d0 + dq * 8 + q;
        float av = ev_[q];
        float ev; bool inc;
        if (s == d) { ev = me_[q]; inc = true; } else { ev = av; inc = av > 0.f; }
        float p = inc ? __expf(lrelu(asv + adv[q] + ev * wE)) : 0.f;
        pq[q] = p;
        zac[q] += p;
      }
      *(float4*)(&pL[ssp][dq * 8])     = make_float4(pq[0], pq[1], pq[2], pq[3]);
      *(float4*)(&pL[ssp][dq * 8 + 4]) = make_float4(pq[4], pq[5], pq[6], pq[7]);
    }
    __syncthreads();
#pragma unroll
    for (int ss = 0; ss < 16; ++ss) {
      float4 pA = *(const float4*)(&pL[ss][dg * 8]);
      float4 pB = *(const float4*)(&pL[ss][dg * 8 + 4]);
      float4 hA = *(const float4*)(&hT[ss][cg * 4]);
      float pv[8] = {pA.x, pA.y, pA.z, pA.w, pB.x, pB.y, pB.z, pB.w};
      float hv[4] = {hA.x, hA.y, hA.z, hA.w};
#pragma unroll
      for (int di = 0; di < 8; ++di)
#pragma unroll
        for (int ci = 0; ci < 4; ++ci) acc[di][ci] += pv[di] * hv[ci];
    }
    __syncthreads();
  }
  float* outp = partials + (size_t)blockIdx.y * ((size_t)N * 64);
#pragma unroll
  for (int di = 0; di < 8; ++di) {
    size_t rowo = (size_t)(d0 + dg * 8 + di) * 64 + cg * 4;
    *(float4*)(outp + rowo) = make_float4(acc[di][0], acc[di][1], acc[di][2], acc[di][3]);
  }
#pragma unroll
  for (int q = 0; q < 8; ++q) {
    float v = zac[q];
    v += __shfl_down(v, 8); v += __shfl_down(v, 4);
    v += __shfl_down(v, 2); v += __shfl_down(v, 1);
    if (ssp == 0) atomicAdd(&z2[d0 + dq * 8 + q], v);
  }
}

// ---------- layer2 finalize + pooled sums (atomics) + last-block final linear ----------
__global__ __launch_bounds__(256) void fin2poolK(const float* __restrict__ partials, const float* __restrict__ z2,
                                                 const float* __restrict__ bias2, const int* __restrict__ bidx,
                                                 const float* __restrict__ W_lin, const float* __restrict__ b_lin,
                                                 float* __restrict__ gsum, float* __restrict__ gcnt,
                                                 int* __restrict__ ticket, float* __restrict__ out) {
  int tid = threadIdx.x;
  int i = blockIdx.x * 256 + tid;
  int d = i >> 6, c = i & 63;
  float s = 0.f;
#pragma unroll
  for (int q = 0; q < 32; ++q) s += partials[(size_t)q * N * 64 + i];
  float a = s / z2[d] + bias2[c];
  float v = a > 0.f ? a : __expf(a) - 1.f;
  int g = bidx[d];
  atomicAdd(&gsum[g * 64 + c], v);
  if (c == 0) atomicAdd(&gcnt[g], 1.f);
  // release: every thread's gsum atomic must be device-visible BEFORE this
  // block's ticket increment. threadfence per-thread, then block barrier,
  // THEN tid0 takes the ticket. (Previous version raced: tid0 could take the
  // ticket before other threads in its block finished their atomics.)
  __threadfence();
  __syncthreads();
  __shared__ int lastSh;
  if (tid == 0) {
    int t = atomicAdd(ticket, 1);
    lastSh = (t == (int)gridDim.x - 1) ? 1 : 0;
  }
  __syncthreads();
  if (lastSh) {
    // all other blocks' atomics are device-visible (release via threadfence +
    // ticket order); read through atomics so values come from the coherent
    // point, not a stale per-XCD L2.
    __shared__ float gm[NG][64];
    __shared__ float cnt_[NG];
    if (tid < NG) cnt_[tid] = atomicAdd(&gcnt[tid], 0.f);
    __syncthreads();
    for (int e = tid; e < NG * 64; e += 256) {
      float sv = atomicAdd(&gsum[e], 0.f);
      gm[e >> 6][e & 63] = sv / fmaxf(cnt_[e >> 6], 1.f);
    }
    __syncthreads();
    if (tid < NG * 10) {
      int b = tid / 10, o = tid % 10;
      float accv = b_lin[o];
      for (int k = 0; k < 64; ++k) accv += gm[b][k] * W_lin[k * 10 + o];
      out[b * 10 + o] = accv;
    }
  }
}

extern "C" void kernel_launch(void* const* d_in, const int* in_sizes, int n_in,
                              void* d_out, int out_size, void* d_ws, size_t ws_size,
                              hipStream_t stream) {
  const float* x        = (const float*)d_in[0];
  const float* attn     = (const float*)d_in[1];
  const int*   bidx     = (const int*)d_in[2];
  const float* w_agg    = (const float*)d_in[3];
  const float* b_agg    = (const float*)d_in[4];
  const float* W1       = (const float*)d_in[5];
  const float* att_src1 = (const float*)d_in[6];
  const float* att_dst1 = (const float*)d_in[7];
  const float* We1      = (const float*)d_in[8];
  const float* att_e1   = (const float*)d_in[9];
  const float* bias1    = (const float*)d_in[10];
  const float* W2       = (const float*)d_in[11];
  const float* att_src2 = (const float*)d_in[12];
  const float* att_dst2 = (const float*)d_in[13];
  const float* We2      = (const float*)d_in[14];
  const float* att_e2   = (const float*)d_in[15];
  const float* bias2    = (const float*)d_in[16];
  const float* W_lin    = (const float*)d_in[17];
  const float* b_lin    = (const float*)d_in[18];

  float* out = (float*)d_out;
  float* edge_out = out + 80;

  float* w = (float*)d_ws;
  size_t o = 0;
  float* zb   = w + o; o += 7 * N + 1024;   // colSum|colCnt|z1(4N)|z2(N)|gsum(512)|gcnt(8)|ticket
  float* wev  = w + o; o += 8;
  float* h1   = w + o; o += (size_t)N * 256;
  float* a_s1 = w + o; o += (size_t)N * 4;
  float* a_d1 = w + o; o += (size_t)N * 4;
  float* hh2  = w + o; o += (size_t)N * 64;
  float* a_s2 = w + o; o += N;
  float* a_d2 = w + o; o += N;
  float* partials = w + o; o += (size_t)16 * N * 256;  // pv2 reuses (needs 32*N*64 = half)

  float* colSum = zb;
  float* colCnt = zb + N;
  float* z1     = zb + 2 * N;
  float* z2     = zb + 6 * N;
  float* gsum   = zb + 7 * N;
  float* gcnt   = zb + 7 * N + 512;
  int*   ticket = (int*)(zb + 7 * N + 520);

  hipMemsetAsync(zb, 0, (7 * N + 1024) * sizeof(float), stream);
  aggh1K<<<4608, 256, 0, stream>>>(attn, w_agg, b_agg, x, W1, att_src1, att_dst1,
                                   We1, att_e1, We2, att_e2,
                                   edge_out, colSum, colCnt, h1, a_s1, a_d1, wev);
  pv1K<<<dim3(32, 16), 256, 0, stream>>>(edge_out, h1, a_s1, a_d1, colSum, colCnt, wev, partials, z1);
  h2K<<<512, 256, 0, stream>>>(partials, z1, bias1, W2, att_src2, att_dst2, hh2, a_s2, a_d2);
  pv2K<<<dim3(16, 32), 256, 0, stream>>>(edge_out, hh2, a_s2, a_d2, colSum, colCnt, wev, partials, z2);
  fin2poolK<<<512, 256, 0, stream>>>(partials, z2, bias2, bidx, W_lin, b_lin, gsum, gcnt, ticket, out);
}